// Round 1
// 441.998 us; speedup vs baseline: 1.0585x; 1.0585x over previous
//
#include <hip/hip_runtime.h>

// out[n,o] = sum_i x[n,i]*W[o,i] + b[o]
// x: 524288x128 fp32, W: 128x128 fp32 (row-major [o][i]), b: 128 fp32, out: 524288x128 fp32
//
// Memory-bound: ~512 MB mandatory HBM traffic -> ~85us floor at 6.3 TB/s.
// v2: W fragments moved from registers (128 VGPRs -> 2 waves/SIMD, 21% occ)
// into LDS (32 KB, pre-swizzled to MFMA B-fragment layout, written once per
// block). Frees the register file -> 4 waves/SIMD target, 8-wave blocks.

typedef __fp16   fp16x2   __attribute__((ext_vector_type(2)));  // cvt_pkrtz result
typedef _Float16 half8_t  __attribute__((ext_vector_type(8)));  // MFMA A/B operand
typedef float    float4_t __attribute__((ext_vector_type(4)));

constexpr int BATCH = 524288;
constexpr int K = 128;
constexpr int N = 128;
constexpr int ROWS_PER_BLOCK_TILE = 128;                   // 8 waves x 16 rows
constexpr int NUM_TILES = BATCH / ROWS_PER_BLOCK_TILE;     // 4096
constexpr int GRID = 1024;
constexpr int TILES_PER_BLOCK = NUM_TILES / GRID;          // 4

__global__ __launch_bounds__(512, 4)
void linear_mfma_kernel(const float* __restrict__ x,
                        const float* __restrict__ W,
                        const float* __restrict__ bias,
                        float* __restrict__ out)
{
    // B-fragment store: slot (t*4 + c)*64 + lane holds the half8
    //   W[o = t*16 + (lane&15)][k = c*32 + (lane>>4)*8 .. +7]
    // Hot-loop read: lane i reads slot base+i -> contiguous 16B/lane, conflict-free.
    __shared__ half8_t lds_w[2048];   // 32 KB

    const int tid  = threadIdx.x;
    const int lane = tid & 63;
    const int wave = tid >> 6;
    const int l15  = lane & 15;   // A: m-row / B: o-col / C: col
    const int quad = lane >> 4;   // A,B: k-subchunk / C: row-quad

    // ---- one-time W fragment fill (coalesced global reads) ----
#pragma unroll
    for (int s = 0; s < 4; ++s) {
        const int g   = tid + s * 512;       // octet id, 0..2047
        const int o   = g >> 4;              // W row
        const int idx = g & 15;
        const int c   = idx >> 2;            // k-chunk of 32
        const int q   = idx & 3;             // k-subchunk of 8
        const float* wp = W + (size_t)o * K + c * 32 + q * 8;
        float4_t w0 = *(const float4_t*)(wp);
        float4_t w1 = *(const float4_t*)(wp + 4);
        union { half8_t v; fp16x2 h[4]; } u;
        u.h[0] = __builtin_amdgcn_cvt_pkrtz(w0.x, w0.y);
        u.h[1] = __builtin_amdgcn_cvt_pkrtz(w0.z, w0.w);
        u.h[2] = __builtin_amdgcn_cvt_pkrtz(w1.x, w1.y);
        u.h[3] = __builtin_amdgcn_cvt_pkrtz(w1.z, w1.w);
        const int t   = o >> 4;
        const int r15 = o & 15;
        lds_w[(t * 4 + c) * 64 + q * 16 + r15] = u.v;
    }

    // bias value per lane per o-tile: col = t*16 + l15
    float bv[8];
#pragma unroll
    for (int t = 0; t < 8; ++t) bv[t] = bias[t * 16 + l15];

    __syncthreads();

    // ---- row-tile loop: 8 waves x 16 rows = 128 rows per iteration ----
#pragma unroll 1
    for (int it = 0; it < TILES_PER_BLOCK; ++it) {
        const int tile = blockIdx.x * TILES_PER_BLOCK + it;
        const int m0 = tile * ROWS_PER_BLOCK_TILE + wave * 16;

        // Opaque zero: makes the LDS fragment addresses loop-variant so the
        // compiler cannot LICM/CSE the 32 ds_read_b128 back into 128 registers.
        int zoff = 0;
        asm volatile("" : "+v"(zoff));
        const half8_t* wf = lds_w + zoff;

        const float* xp = x + (size_t)(m0 + l15) * K + quad * 8;

        float4_t acc[8];
#pragma unroll
        for (int t = 0; t < 8; ++t) acc[t] = (float4_t)0.0f;

#pragma unroll
        for (int c = 0; c < 4; ++c) {
            float4_t a0 = *(const float4_t*)(xp + c * 32);
            float4_t a1 = *(const float4_t*)(xp + c * 32 + 4);
            union { half8_t v; fp16x2 h[4]; } ua;
            ua.h[0] = __builtin_amdgcn_cvt_pkrtz(a0.x, a0.y);
            ua.h[1] = __builtin_amdgcn_cvt_pkrtz(a0.z, a0.w);
            ua.h[2] = __builtin_amdgcn_cvt_pkrtz(a1.x, a1.y);
            ua.h[3] = __builtin_amdgcn_cvt_pkrtz(a1.z, a1.w);
#pragma unroll
            for (int t = 0; t < 8; ++t) {
                half8_t bf = wf[(t * 4 + c) * 64 + lane];
                acc[t] = __builtin_amdgcn_mfma_f32_16x16x32_f16(ua.v, bf, acc[t], 0, 0, 0);
            }
        }

        // C/D layout: row = quad*4 + r, col = t*16 + l15
        float* op = out + (size_t)(m0 + quad * 4) * N + l15;
#pragma unroll
        for (int t = 0; t < 8; ++t) {
#pragma unroll
            for (int r = 0; r < 4; ++r) {
                op[(size_t)r * N + t * 16] = acc[t][r] + bv[t];
            }
        }
    }
}

extern "C" void kernel_launch(void* const* d_in, const int* in_sizes, int n_in,
                              void* d_out, int out_size, void* d_ws, size_t ws_size,
                              hipStream_t stream) {
    const float* x = (const float*)d_in[0];
    const float* W = (const float*)d_in[1];
    const float* b = (const float*)d_in[2];
    float* out = (float*)d_out;
    linear_mfma_kernel<<<GRID, 512, 0, stream>>>(x, W, b, out);
}